// Round 2
// baseline (362.606 us; speedup 1.0000x reference)
//
#include <hip/hip_runtime.h>
#include <stdint.h>

#define SLOPE 0.2f
#define HASH_SIZE 131072  // 2^17, load factor ~0.38 at C=50000

__device__ __forceinline__ float leakyf(float x) { return x >= 0.f ? x : SLOPE * x; }
__device__ __forceinline__ float sigmoidf(float x) { return 1.f / (1.f + expf(-x)); }

// ---------- init scratch (deg/cursor zero, hash empty) ----------
__global__ void init_kernel(int* __restrict__ deg, int* __restrict__ cursor,
                            int* __restrict__ hkeys, float* __restrict__ hval,
                            int n, int H)
{
  int i = blockIdx.x * blockDim.x + threadIdx.x;
  int stride = gridDim.x * blockDim.x;
  for (int j = i; j < n; j += stride) { deg[j] = 0; cursor[j] = 0; }
  for (int j = i; j < H; j += stride) { hkeys[j] = -1; hval[j] = 0.f; }
}

// ---------- constraint hash build ----------
__global__ void hash_build(const int* __restrict__ cidx, const float* __restrict__ cval,
                           const int* __restrict__ ctype, const float* __restrict__ lc,
                           int* __restrict__ hkeys, float* __restrict__ hval,
                           int C, int n, int H)
{
  int i = blockIdx.x * blockDim.x + threadIdx.x;
  if (i >= C) return;
  int key = cidx[i] * n + cidx[C + i];
  float l = sigmoidf(lc[ctype[i]]) * 0.9f + 0.1f;   // lc = sig*(1-0.1)+0.1
  float w = l * cval[i];
  unsigned int slot = ((unsigned int)key * 2654435761u) & (unsigned int)(H - 1);
  while (true) {
    int prev = atomicCAS(&hkeys[slot], -1, key);
    if (prev == -1 || prev == key) break;
    slot = (slot + 1) & (unsigned int)(H - 1);
  }
  atomicAdd(&hval[slot], w);
}

// ---------- per-relation precompute: P3b[r][j] = rel[r]·att_w1[j,256:384] + att_b1[j] ----------
__global__ __launch_bounds__(128) void p3b_kernel(const float* __restrict__ rel,
                                                  const float* __restrict__ aw1,
                                                  const float* __restrict__ ab1,
                                                  float* __restrict__ P3b)
{
  int r = blockIdx.x; int j = threadIdx.x;
  __shared__ float rl[128];
  rl[j] = rel[r * 128 + j];
  __syncthreads();
  float acc = ab1[j];
  const float* wrow = aw1 + j * 384 + 256;
  #pragma unroll 4
  for (int k = 0; k < 128; ++k) acc += rl[k] * wrow[k];
  P3b[r * 128 + j] = acc;
}

// ---------- GEMM: C[MxN=128] = A[Mx128] @ B^T, B row j uses cols [boff, boff+128) of ldb-stride rows
// epi==0: store fp32 to Cb.  epi==1: final fused epilogue -> outp (fp32)
__global__ __launch_bounds__(256) void gemm_abt(
    const float* __restrict__ A,
    const float* __restrict__ B, int ldb, int boff, int M,
    float* __restrict__ Cb, int epi,
    const float* __restrict__ Whb,
    const float* __restrict__ side,
    float* __restrict__ outp)
{
  __shared__ float As[16][68];
  __shared__ float Bs[16][68];
  const int tid = threadIdx.x;
  const int tx = tid & 15, ty = tid >> 4;
  const int m0 = blockIdx.x * 64;
  const int n0 = blockIdx.y * 64;
  float acc[4][4] = {};
  const int lin = tid * 4;
  const int lm = lin >> 4;        // 0..63
  const int lk = lin & 15;        // 0,4,8,12

  for (int kk = 0; kk < 128; kk += 16) {
    __syncthreads();
    {
      int row = m0 + lm;
      if (row < M) {
        float4 v = *(const float4*)(A + row * 128 + kk + lk);
        As[lk + 0][lm] = v.x; As[lk + 1][lm] = v.y;
        As[lk + 2][lm] = v.z; As[lk + 3][lm] = v.w;
      } else {
        As[lk + 0][lm] = 0.f; As[lk + 1][lm] = 0.f;
        As[lk + 2][lm] = 0.f; As[lk + 3][lm] = 0.f;
      }
      int j = n0 + lm;  // N=128 exact, no guard needed
      float4 w = *(const float4*)(B + j * ldb + boff + kk + lk);
      Bs[lk + 0][lm] = w.x; Bs[lk + 1][lm] = w.y;
      Bs[lk + 2][lm] = w.z; Bs[lk + 3][lm] = w.w;
    }
    __syncthreads();
    #pragma unroll
    for (int k = 0; k < 16; ++k) {
      float a[4], b[4];
      #pragma unroll
      for (int i = 0; i < 4; ++i) a[i] = As[k][ty * 4 + i];
      #pragma unroll
      for (int j = 0; j < 4; ++j) b[j] = Bs[k][tx * 4 + j];
      #pragma unroll
      for (int i = 0; i < 4; ++i)
        #pragma unroll
        for (int j = 0; j < 4; ++j)
          acc[i][j] += a[i] * b[j];
    }
  }

  #pragma unroll
  for (int i = 0; i < 4; ++i) {
    int row = m0 + ty * 4 + i;
    if (row >= M) continue;
    #pragma unroll
    for (int j = 0; j < 4; ++j) {
      int col = n0 + tx * 4 + j;
      float v = acc[i][j];
      int idx = row * 128 + col;
      if (epi == 0) {
        Cb[idx] = v;
      } else {
        float w = Whb[idx];
        float s = side[idx];
        float hn = leakyf(w + s) + leakyf(v) + w;
        float o = hn > 0.f ? hn : (expf(hn) - 1.f);
        outp[idx] = o;
      }
    }
  }
}

// ---------- per-edge: e = leaky(P1[src]+P2[tgt]+P3b[rt])·aw2 ; constraint+gate term; deg count ----------
__global__ __launch_bounds__(256) void edge_kernel(
  const int* __restrict__ ei, const int* __restrict__ etype,
  const float* __restrict__ P1, const float* __restrict__ P2,
  const float* __restrict__ P3b,
  const float* __restrict__ Q1, const float* __restrict__ Q2,
  const float* __restrict__ aw2,
  const float* __restrict__ gb1, const float* __restrict__ gw2,
  const float* __restrict__ gb2, const float* __restrict__ lgp,
  const int* __restrict__ hkeys, const float* __restrict__ hval,
  float* __restrict__ e_buf, int* __restrict__ deg,
  int E, int n, int H)
{
  int wid = blockIdx.x * 4 + ((int)threadIdx.x >> 6);
  if (wid >= E) return;
  int lane = threadIdx.x & 63;
  int src = ei[wid], tgt = ei[E + wid], rt = etype[wid];

  float2 p1 = *(const float2*)(P1 + src * 128 + 2 * lane);
  float2 p2 = *(const float2*)(P2 + tgt * 128 + 2 * lane);
  float2 p3 = *(const float2*)(P3b + rt * 128 + 2 * lane);
  float hx = leakyf(p1.x + p2.x + p3.x);
  float hy = leakyf(p1.y + p2.y + p3.y);
  float2 w2 = *(const float2*)(aw2 + 2 * lane);
  float part = hx * w2.x + hy * w2.y;
  #pragma unroll
  for (int k = 32; k; k >>= 1) part += __shfl_xor(part, k, 64);
  float e = part;

  // hash lookup: mask & c_agg
  int key = src * n + tgt;
  unsigned int slot = ((unsigned int)key * 2654435761u) & (unsigned int)(H - 1);
  int fslot = -1;
  while (true) {
    int kk = hkeys[slot];
    if (kk == key) { fslot = (int)slot; break; }
    if (kk == -1) break;
    slot = (slot + 1) & (unsigned int)(H - 1);
  }
  if (fslot >= 0) {  // wave-uniform branch (whole wave = one edge)
    float ms = hval[fslot];
    float2 q1 = *(const float2*)(Q1 + src * 128 + 2 * lane);
    float2 q2 = *(const float2*)(Q2 + tgt * 128 + 2 * lane);
    float2 b1 = *(const float2*)(gb1 + 2 * lane);
    float gx = leakyf(q1.x + q2.x + b1.x);
    float gy = leakyf(q1.y + q2.y + b1.y);
    float2 g2 = *(const float2*)(gw2 + 2 * lane);
    float gp = gx * g2.x + gy * g2.y;
    #pragma unroll
    for (int k = 32; k; k >>= 1) gp += __shfl_xor(gp, k, 64);
    float g = sigmoidf(gp + gb2[0]);
    float lg = sigmoidf(lgp[0]) * 0.9f + 0.1f;
    e += lg * (g * ms);    // n_matched > 0 structurally (constraints copy first C edges)
  }
  if (lane == 0) {
    e_buf[wid] = e;
    atomicAdd(&deg[src], 1);
  }
}

// ---------- exclusive scan of deg -> offs (single block) ----------
__global__ __launch_bounds__(1024) void scan_kernel(const int* __restrict__ deg,
                                                    int* __restrict__ offs, int n)
{
  __shared__ int buf[1024];
  __shared__ int carry;
  if (threadIdx.x == 0) carry = 0;
  __syncthreads();
  for (int base = 0; base < n; base += 1024) {
    int i = base + (int)threadIdx.x;
    int v = (i < n) ? deg[i] : 0;
    buf[threadIdx.x] = v;
    __syncthreads();
    for (int offd = 1; offd < 1024; offd <<= 1) {
      int tv = (threadIdx.x >= (unsigned)offd) ? buf[threadIdx.x - offd] : 0;
      __syncthreads();
      buf[threadIdx.x] += tv;
      __syncthreads();
    }
    if (i < n) offs[i] = carry + buf[threadIdx.x] - v;
    __syncthreads();
    if (threadIdx.x == 0) carry += buf[1023];
    __syncthreads();
  }
}

// ---------- bucket edges by src ----------
__global__ void place_kernel(const int* __restrict__ ei, const int* __restrict__ offs,
                             int* __restrict__ cursor, int* __restrict__ eids, int E)
{
  int i = blockIdx.x * blockDim.x + threadIdx.x;
  if (i >= E) return;
  int s = ei[i];
  int pos = offs[s] + atomicAdd(&cursor[s], 1);
  eids[pos] = i;
}

// ---------- per-node softmax + aggregation; writes side (fp32) and X = Wh*side ----------
__global__ __launch_bounds__(128) void node_kernel(
  const int* __restrict__ offs, const int* __restrict__ deg,
  const int* __restrict__ eids, const int* __restrict__ ei,
  const float* __restrict__ e_buf, const float* __restrict__ Whb,
  float* __restrict__ side, float* __restrict__ Xb, int E)
{
  const int node = blockIdx.x;
  const int t = threadIdx.x;
  const int start = offs[node];
  const int cnt = deg[node];
  __shared__ float red2[2];
  __shared__ int sh_t[128];
  __shared__ float sh_e[128];

  float m = -INFINITY;
  for (int j = t; j < cnt; j += 128) m = fmaxf(m, e_buf[eids[start + j]]);
  #pragma unroll
  for (int k = 32; k; k >>= 1) m = fmaxf(m, __shfl_xor(m, k, 64));
  if ((t & 63) == 0) red2[t >> 6] = m;
  __syncthreads();
  m = fmaxf(red2[0], red2[1]);

  float acc = 0.f, ssum = 0.f;
  for (int base = 0; base < cnt; base += 128) {
    int jmax = min(128, cnt - base);
    __syncthreads();
    if (t < jmax) {
      int eid = eids[start + base + t];
      sh_t[t] = ei[E + eid];
      sh_e[t] = e_buf[eid];
    }
    __syncthreads();
    for (int j = 0; j < jmax; ++j) {
      float ex = expf(fminf(sh_e[j] - m, 20.f));
      ssum += ex;
      acc += ex * Whb[sh_t[j] * 128 + t];
    }
  }
  float s = acc / (ssum + 1e-10f);
  int idx = node * 128 + t;
  side[idx] = s;
  Xb[idx] = Whb[idx] * s;
}

// ---------- launch ----------
extern "C" void kernel_launch(void* const* d_in, const int* in_sizes, int n_in,
                              void* d_out, int out_size, void* d_ws, size_t ws_size,
                              hipStream_t stream)
{
  const float* h    = (const float*)d_in[0];
  const int* ei     = (const int*)d_in[1];
  const int* etype  = (const int*)d_in[2];
  const float* rel  = (const float*)d_in[3];
  const int* cidx   = (const int*)d_in[4];
  const float* cval = (const float*)d_in[5];
  const int* ctype  = (const int*)d_in[6];
  const float* W    = (const float*)d_in[7];
  const float* Wbi  = (const float*)d_in[8];
  const float* aw1  = (const float*)d_in[9];
  const float* ab1  = (const float*)d_in[10];
  const float* aw2  = (const float*)d_in[11];
  const float* gw1  = (const float*)d_in[12];
  const float* gb1  = (const float*)d_in[13];
  const float* gw2  = (const float*)d_in[14];
  const float* gb2  = (const float*)d_in[15];
  const float* lc   = (const float*)d_in[16];
  const float* lgp  = (const float*)d_in[17];

  const int n = in_sizes[0] / 128;   // 10000
  const int E = in_sizes[2];         // 320000
  const int C = in_sizes[6];         // 50000
  const int R = in_sizes[3] / 128;   // 20
  const int H = HASH_SIZE;

  // scratch layout (~40 MB)
  char* ws = (char*)d_ws;
  size_t off = 0;
  auto alloc = [&](size_t bytes) -> void* {
    void* p = ws + off;
    off = (off + bytes + 255) & ~(size_t)255;
    return p;
  };
  float* Whb = (float*)alloc((size_t)n * 128 * 4);
  float* P1  = (float*)alloc((size_t)n * 128 * 4);
  float* P2  = (float*)alloc((size_t)n * 128 * 4);
  float* Q1  = (float*)alloc((size_t)n * 128 * 4);
  float* Q2  = (float*)alloc((size_t)n * 128 * 4);
  float* Xb  = (float*)alloc((size_t)n * 128 * 4);
  float* P3b = (float*)alloc((size_t)R * 128 * 4);
  float* e_buf = (float*)alloc((size_t)E * 4);
  float* side  = (float*)alloc((size_t)n * 128 * 4);
  int* deg     = (int*)alloc((size_t)n * 4);
  int* cursor  = (int*)alloc((size_t)n * 4);
  int* offs    = (int*)alloc((size_t)(n + 1) * 4);
  int* eids    = (int*)alloc((size_t)E * 4);
  int* hkeys   = (int*)alloc((size_t)H * 4);
  float* hval  = (float*)alloc((size_t)H * 4);
  (void)ws_size; (void)n_in; (void)out_size;

  dim3 gblk(256);
  dim3 ggrid((n + 63) / 64, 2);

  init_kernel<<<256, 256, 0, stream>>>(deg, cursor, hkeys, hval, n, H);
  hash_build<<<(C + 255) / 256, 256, 0, stream>>>(cidx, cval, ctype, lc, hkeys, hval, C, n, H);

  // Wh = h @ W^T
  gemm_abt<<<ggrid, gblk, 0, stream>>>(h, W, 128, 0, n, Whb, 0, nullptr, nullptr, nullptr);
  p3b_kernel<<<R, 128, 0, stream>>>(rel, aw1, ab1, P3b);
  // P1 = Wh@A1^T, P2 = Wh@A2^T, Q1 = Wh@G1^T, Q2 = Wh@G2^T
  gemm_abt<<<ggrid, gblk, 0, stream>>>(Whb, aw1, 384, 0,   n, P1, 0, nullptr, nullptr, nullptr);
  gemm_abt<<<ggrid, gblk, 0, stream>>>(Whb, aw1, 384, 128, n, P2, 0, nullptr, nullptr, nullptr);
  gemm_abt<<<ggrid, gblk, 0, stream>>>(Whb, gw1, 256, 0,   n, Q1, 0, nullptr, nullptr, nullptr);
  gemm_abt<<<ggrid, gblk, 0, stream>>>(Whb, gw1, 256, 128, n, Q2, 0, nullptr, nullptr, nullptr);

  edge_kernel<<<(E + 3) / 4, 256, 0, stream>>>(ei, etype, P1, P2, P3b, Q1, Q2, aw2,
                                               gb1, gw2, gb2, lgp, hkeys, hval,
                                               e_buf, deg, E, n, H);
  scan_kernel<<<1, 1024, 0, stream>>>(deg, offs, n);
  place_kernel<<<(E + 255) / 256, 256, 0, stream>>>(ei, offs, cursor, eids, E);
  node_kernel<<<n, 128, 0, stream>>>(offs, deg, eids, ei, e_buf, Whb, side, Xb, E);

  // bi = X @ W_bi^T ; out = elu(leaky(Wh+side) + leaky(bi) + Wh)
  gemm_abt<<<ggrid, gblk, 0, stream>>>(Xb, Wbi, 128, 0, n, nullptr, 1, Whb, side,
                                       (float*)d_out);
}

// Round 3
// 298.563 us; speedup vs baseline: 1.2145x; 1.2145x over previous
//
#include <hip/hip_runtime.h>
#include <stdint.h>

#define SLOPE 0.2f
#define HASH_SIZE 131072  // 2^17, load factor ~0.38 at C=50000

__device__ __forceinline__ float leakyf(float x) { return x >= 0.f ? x : SLOPE * x; }
__device__ __forceinline__ float sigmoidf(float x) { return 1.f / (1.f + expf(-x)); }

// ---------- init scratch (deg/cursor zero, hash empty) ----------
__global__ void init_kernel(int* __restrict__ deg, int* __restrict__ cursor,
                            int* __restrict__ hkeys, float* __restrict__ hval,
                            int n, int H)
{
  int i = blockIdx.x * blockDim.x + threadIdx.x;
  int stride = gridDim.x * blockDim.x;
  for (int j = i; j < n; j += stride) { deg[j] = 0; cursor[j] = 0; }
  for (int j = i; j < H; j += stride) { hkeys[j] = -1; hval[j] = 0.f; }
}

// ---------- constraint hash build ----------
__global__ void hash_build(const int* __restrict__ cidx, const float* __restrict__ cval,
                           const int* __restrict__ ctype, const float* __restrict__ lc,
                           int* __restrict__ hkeys, float* __restrict__ hval,
                           int C, int n, int H)
{
  int i = blockIdx.x * blockDim.x + threadIdx.x;
  if (i >= C) return;
  int key = cidx[i] * n + cidx[C + i];
  float l = sigmoidf(lc[ctype[i]]) * 0.9f + 0.1f;   // lc = sig*(1-0.1)+0.1
  float w = l * cval[i];
  unsigned int slot = ((unsigned int)key * 2654435761u) & (unsigned int)(H - 1);
  while (true) {
    int prev = atomicCAS(&hkeys[slot], -1, key);
    if (prev == -1 || prev == key) break;
    slot = (slot + 1) & (unsigned int)(H - 1);
  }
  atomicAdd(&hval[slot], w);
}

// ---------- per-relation precompute: P3b[r][j] = rel[r]·att_w1[j,256:384] + att_b1[j] ----------
__global__ __launch_bounds__(128) void p3b_kernel(const float* __restrict__ rel,
                                                  const float* __restrict__ aw1,
                                                  const float* __restrict__ ab1,
                                                  float* __restrict__ P3b)
{
  int r = blockIdx.x; int j = threadIdx.x;
  __shared__ float rl[128];
  rl[j] = rel[r * 128 + j];
  __syncthreads();
  float acc = ab1[j];
  const float* wrow = aw1 + j * 384 + 256;
  #pragma unroll 4
  for (int k = 0; k < 128; ++k) acc += rl[k] * wrow[k];
  P3b[r * 128 + j] = acc;
}

// ---------- shared GEMM body (64x64 tile, 4x4 microtile, K=128) ----------
__device__ __forceinline__ void gemm_body(
    const float* __restrict__ A, const float* __restrict__ B,
    int ldb, int boff, int M, int m0, int n0,
    float (&acc)[4][4], float (*As)[68], float (*Bs)[68])
{
  const int tid = threadIdx.x;
  const int tx = tid & 15, ty = tid >> 4;
  const int lin = tid * 4;
  const int lm = lin >> 4;        // 0..63
  const int lk = lin & 15;        // 0,4,8,12

  for (int kk = 0; kk < 128; kk += 16) {
    __syncthreads();
    {
      int row = m0 + lm;
      if (row < M) {
        float4 v = *(const float4*)(A + row * 128 + kk + lk);
        As[lk + 0][lm] = v.x; As[lk + 1][lm] = v.y;
        As[lk + 2][lm] = v.z; As[lk + 3][lm] = v.w;
      } else {
        As[lk + 0][lm] = 0.f; As[lk + 1][lm] = 0.f;
        As[lk + 2][lm] = 0.f; As[lk + 3][lm] = 0.f;
      }
      int j = n0 + lm;  // N=128 exact, no guard needed
      float4 w = *(const float4*)(B + j * ldb + boff + kk + lk);
      Bs[lk + 0][lm] = w.x; Bs[lk + 1][lm] = w.y;
      Bs[lk + 2][lm] = w.z; Bs[lk + 3][lm] = w.w;
    }
    __syncthreads();
    #pragma unroll
    for (int k = 0; k < 16; ++k) {
      float a[4], b[4];
      #pragma unroll
      for (int i = 0; i < 4; ++i) a[i] = As[k][ty * 4 + i];
      #pragma unroll
      for (int j = 0; j < 4; ++j) b[j] = Bs[k][tx * 4 + j];
      #pragma unroll
      for (int i = 0; i < 4; ++i)
        #pragma unroll
        for (int j = 0; j < 4; ++j)
          acc[i][j] += a[i] * b[j];
    }
  }
}

// ---------- GEMM: C = A @ B^T (plain store, or fused final epilogue) ----------
__global__ __launch_bounds__(256) void gemm_abt(
    const float* __restrict__ A,
    const float* __restrict__ B, int ldb, int boff, int M,
    float* __restrict__ Cb, int epi,
    const float* __restrict__ Whb,
    const float* __restrict__ side,
    float* __restrict__ outp)
{
  __shared__ float As[16][68];
  __shared__ float Bs[16][68];
  const int m0 = blockIdx.x * 64;
  const int n0 = blockIdx.y * 64;
  float acc[4][4] = {};
  gemm_body(A, B, ldb, boff, M, m0, n0, acc, As, Bs);

  const int tx = (int)threadIdx.x & 15, ty = (int)threadIdx.x >> 4;
  #pragma unroll
  for (int i = 0; i < 4; ++i) {
    int row = m0 + ty * 4 + i;
    if (row >= M) continue;
    #pragma unroll
    for (int j = 0; j < 4; ++j) {
      int col = n0 + tx * 4 + j;
      float v = acc[i][j];
      int idx = row * 128 + col;
      if (epi == 0) {
        Cb[idx] = v;
      } else {
        float w = Whb[idx];
        float s = side[idx];
        float hn = leakyf(w + s) + leakyf(v) + w;
        float o = hn > 0.f ? hn : (expf(hn) - 1.f);
        outp[idx] = o;
      }
    }
  }
}

// ---------- fused 4-matrix GEMM: P1/P2 = Wh@A1/A2^T, Q1/Q2 = Wh@G1/G2^T ----------
__global__ __launch_bounds__(256) void gemm4(
    const float* __restrict__ A,
    const float* __restrict__ aw1, const float* __restrict__ gw1,
    float* __restrict__ P1, float* __restrict__ P2,
    float* __restrict__ Q1, float* __restrict__ Q2, int M)
{
  __shared__ float As[16][68];
  __shared__ float Bs[16][68];
  const int mat = blockIdx.y >> 1;
  const int n0 = (blockIdx.y & 1) * 64;
  const int m0 = blockIdx.x * 64;
  const float* B; int ldb, boff; float* out;
  switch (mat) {
    case 0:  B = aw1; ldb = 384; boff = 0;   out = P1; break;
    case 1:  B = aw1; ldb = 384; boff = 128; out = P2; break;
    case 2:  B = gw1; ldb = 256; boff = 0;   out = Q1; break;
    default: B = gw1; ldb = 256; boff = 128; out = Q2; break;
  }
  float acc[4][4] = {};
  gemm_body(A, B, ldb, boff, M, m0, n0, acc, As, Bs);

  const int tx = (int)threadIdx.x & 15, ty = (int)threadIdx.x >> 4;
  #pragma unroll
  for (int i = 0; i < 4; ++i) {
    int row = m0 + ty * 4 + i;
    if (row >= M) continue;
    #pragma unroll
    for (int j = 0; j < 4; ++j)
      out[row * 128 + n0 + tx * 4 + j] = acc[i][j];
  }
}

// ---------- per-edge: 32 lanes per edge, float4 per lane ----------
__global__ __launch_bounds__(256) void edge_kernel(
  const int* __restrict__ ei, const int* __restrict__ etype,
  const float* __restrict__ P1, const float* __restrict__ P2,
  const float* __restrict__ P3b,
  const float* __restrict__ Q1, const float* __restrict__ Q2,
  const float* __restrict__ aw2,
  const float* __restrict__ gb1, const float* __restrict__ gw2,
  const float* __restrict__ gb2, const float* __restrict__ lgp,
  const int* __restrict__ hkeys, const float* __restrict__ hval,
  float* __restrict__ e_buf, int* __restrict__ deg,
  int E, int n, int H)
{
  int wid = blockIdx.x * 8 + ((int)threadIdx.x >> 5);   // edge id, 8 per block
  if (wid >= E) return;
  int l = threadIdx.x & 31;                              // lane within edge group
  int src = ei[wid], tgt = ei[E + wid], rt = etype[wid];

  float4 p1 = *(const float4*)(P1 + src * 128 + 4 * l);
  float4 p2 = *(const float4*)(P2 + tgt * 128 + 4 * l);
  float4 p3 = *(const float4*)(P3b + rt * 128 + 4 * l);
  float4 w2 = *(const float4*)(aw2 + 4 * l);
  float part = leakyf(p1.x + p2.x + p3.x) * w2.x
             + leakyf(p1.y + p2.y + p3.y) * w2.y
             + leakyf(p1.z + p2.z + p3.z) * w2.z
             + leakyf(p1.w + p2.w + p3.w) * w2.w;
  #pragma unroll
  for (int k = 16; k; k >>= 1) part += __shfl_xor(part, k, 64);  // masks<32: stays in half-wave
  float e = part;

  // hash lookup: mask & c_agg
  int key = src * n + tgt;
  unsigned int slot = ((unsigned int)key * 2654435761u) & (unsigned int)(H - 1);
  int fslot = -1;
  while (true) {
    int kk = hkeys[slot];
    if (kk == key) { fslot = (int)slot; break; }
    if (kk == -1) break;
    slot = (slot + 1) & (unsigned int)(H - 1);
  }
  if (fslot >= 0) {  // half-wave-uniform branch
    float ms = hval[fslot];
    float4 q1 = *(const float4*)(Q1 + src * 128 + 4 * l);
    float4 q2 = *(const float4*)(Q2 + tgt * 128 + 4 * l);
    float4 b1 = *(const float4*)(gb1 + 4 * l);
    float4 g2 = *(const float4*)(gw2 + 4 * l);
    float gp = leakyf(q1.x + q2.x + b1.x) * g2.x
             + leakyf(q1.y + q2.y + b1.y) * g2.y
             + leakyf(q1.z + q2.z + b1.z) * g2.z
             + leakyf(q1.w + q2.w + b1.w) * g2.w;
    #pragma unroll
    for (int k = 16; k; k >>= 1) gp += __shfl_xor(gp, k, 64);
    float g = sigmoidf(gp + gb2[0]);
    float lg = sigmoidf(lgp[0]) * 0.9f + 0.1f;
    e += lg * (g * ms);    // n_matched > 0 structurally (constraints copy first C edges)
  }
  if (l == 0) {
    e_buf[wid] = e;
    atomicAdd(&deg[src], 1);
  }
}

// ---------- exclusive scan of deg -> offs (single block) ----------
__global__ __launch_bounds__(1024) void scan_kernel(const int* __restrict__ deg,
                                                    int* __restrict__ offs, int n)
{
  __shared__ int buf[1024];
  __shared__ int carry;
  if (threadIdx.x == 0) carry = 0;
  __syncthreads();
  for (int base = 0; base < n; base += 1024) {
    int i = base + (int)threadIdx.x;
    int v = (i < n) ? deg[i] : 0;
    buf[threadIdx.x] = v;
    __syncthreads();
    for (int offd = 1; offd < 1024; offd <<= 1) {
      int tv = (threadIdx.x >= (unsigned)offd) ? buf[threadIdx.x - offd] : 0;
      __syncthreads();
      buf[threadIdx.x] += tv;
      __syncthreads();
    }
    if (i < n) offs[i] = carry + buf[threadIdx.x] - v;
    __syncthreads();
    if (threadIdx.x == 0) carry += buf[1023];
    __syncthreads();
  }
}

// ---------- bucket edges by src ----------
__global__ void place_kernel(const int* __restrict__ ei, const int* __restrict__ offs,
                             int* __restrict__ cursor, int* __restrict__ eids, int E)
{
  int i = blockIdx.x * blockDim.x + threadIdx.x;
  if (i >= E) return;
  int s = ei[i];
  int pos = offs[s] + atomicAdd(&cursor[s], 1);
  eids[pos] = i;
}

// ---------- per-node softmax + aggregation; exp hoisted, gather unrolled x4 ----------
__global__ __launch_bounds__(128) void node_kernel(
  const int* __restrict__ offs, const int* __restrict__ deg,
  const int* __restrict__ eids, const int* __restrict__ ei,
  const float* __restrict__ e_buf, const float* __restrict__ Whb,
  float* __restrict__ side, float* __restrict__ Xb, int E)
{
  const int node = blockIdx.x;
  const int t = threadIdx.x;
  const int start = offs[node];
  const int cnt = deg[node];
  __shared__ float red2[2];
  __shared__ int sh_t[128];
  __shared__ float sh_e[128];

  float m = -INFINITY;
  for (int j = t; j < cnt; j += 128) m = fmaxf(m, e_buf[eids[start + j]]);
  #pragma unroll
  for (int k = 32; k; k >>= 1) m = fmaxf(m, __shfl_xor(m, k, 64));
  if ((t & 63) == 0) red2[t >> 6] = m;
  __syncthreads();
  m = fmaxf(red2[0], red2[1]);

  float acc = 0.f, ssum = 0.f;
  for (int base = 0; base < cnt; base += 128) {
    int jmax = min(128, cnt - base);
    __syncthreads();
    if (t < jmax) {
      int eid = eids[start + base + t];
      sh_t[t] = ei[E + eid] * 128;
      sh_e[t] = expf(fminf(e_buf[eid] - m, 20.f));   // exp once per edge
    }
    __syncthreads();
    int j = 0;
    for (; j + 4 <= jmax; j += 4) {
      int t0 = sh_t[j], t1 = sh_t[j+1], t2 = sh_t[j+2], t3 = sh_t[j+3];
      float e0 = sh_e[j], e1 = sh_e[j+1], e2 = sh_e[j+2], e3 = sh_e[j+3];
      float w0 = Whb[t0 + t], w1 = Whb[t1 + t], w2 = Whb[t2 + t], w3 = Whb[t3 + t];
      ssum += (e0 + e1) + (e2 + e3);
      acc += e0 * w0 + e1 * w1 + e2 * w2 + e3 * w3;
    }
    for (; j < jmax; ++j) {
      float ex = sh_e[j];
      ssum += ex;
      acc += ex * Whb[sh_t[j] + t];
    }
  }
  float s = acc / (ssum + 1e-10f);
  int idx = node * 128 + t;
  side[idx] = s;
  Xb[idx] = Whb[idx] * s;
}

// ---------- launch ----------
extern "C" void kernel_launch(void* const* d_in, const int* in_sizes, int n_in,
                              void* d_out, int out_size, void* d_ws, size_t ws_size,
                              hipStream_t stream)
{
  const float* h    = (const float*)d_in[0];
  const int* ei     = (const int*)d_in[1];
  const int* etype  = (const int*)d_in[2];
  const float* rel  = (const float*)d_in[3];
  const int* cidx   = (const int*)d_in[4];
  const float* cval = (const float*)d_in[5];
  const int* ctype  = (const int*)d_in[6];
  const float* W    = (const float*)d_in[7];
  const float* Wbi  = (const float*)d_in[8];
  const float* aw1  = (const float*)d_in[9];
  const float* ab1  = (const float*)d_in[10];
  const float* aw2  = (const float*)d_in[11];
  const float* gw1  = (const float*)d_in[12];
  const float* gb1  = (const float*)d_in[13];
  const float* gw2  = (const float*)d_in[14];
  const float* gb2  = (const float*)d_in[15];
  const float* lc   = (const float*)d_in[16];
  const float* lgp  = (const float*)d_in[17];

  const int n = in_sizes[0] / 128;   // 10000
  const int E = in_sizes[2];         // 320000
  const int C = in_sizes[6];         // 50000
  const int R = in_sizes[3] / 128;   // 20
  const int H = HASH_SIZE;

  // scratch layout (~40 MB)
  char* ws = (char*)d_ws;
  size_t off = 0;
  auto alloc = [&](size_t bytes) -> void* {
    void* p = ws + off;
    off = (off + bytes + 255) & ~(size_t)255;
    return p;
  };
  float* Whb = (float*)alloc((size_t)n * 128 * 4);
  float* P1  = (float*)alloc((size_t)n * 128 * 4);
  float* P2  = (float*)alloc((size_t)n * 128 * 4);
  float* Q1  = (float*)alloc((size_t)n * 128 * 4);
  float* Q2  = (float*)alloc((size_t)n * 128 * 4);
  float* Xb  = (float*)alloc((size_t)n * 128 * 4);
  float* P3b = (float*)alloc((size_t)R * 128 * 4);
  float* e_buf = (float*)alloc((size_t)E * 4);
  float* side  = (float*)alloc((size_t)n * 128 * 4);
  int* deg     = (int*)alloc((size_t)n * 4);
  int* cursor  = (int*)alloc((size_t)n * 4);
  int* offs    = (int*)alloc((size_t)(n + 1) * 4);
  int* eids    = (int*)alloc((size_t)E * 4);
  int* hkeys   = (int*)alloc((size_t)H * 4);
  float* hval  = (float*)alloc((size_t)H * 4);
  (void)ws_size; (void)n_in; (void)out_size;

  dim3 gblk(256);
  dim3 ggrid((n + 63) / 64, 2);

  init_kernel<<<256, 256, 0, stream>>>(deg, cursor, hkeys, hval, n, H);
  hash_build<<<(C + 255) / 256, 256, 0, stream>>>(cidx, cval, ctype, lc, hkeys, hval, C, n, H);

  // Wh = h @ W^T
  gemm_abt<<<ggrid, gblk, 0, stream>>>(h, W, 128, 0, n, Whb, 0, nullptr, nullptr, nullptr);
  p3b_kernel<<<R, 128, 0, stream>>>(rel, aw1, ab1, P3b);
  // P1,P2,Q1,Q2 in one dispatch
  gemm4<<<dim3((n + 63) / 64, 8), gblk, 0, stream>>>(Whb, aw1, gw1, P1, P2, Q1, Q2, n);

  edge_kernel<<<(E + 7) / 8, 256, 0, stream>>>(ei, etype, P1, P2, P3b, Q1, Q2, aw2,
                                               gb1, gw2, gb2, lgp, hkeys, hval,
                                               e_buf, deg, E, n, H);
  scan_kernel<<<1, 1024, 0, stream>>>(deg, offs, n);
  place_kernel<<<(E + 255) / 256, 256, 0, stream>>>(ei, offs, cursor, eids, E);
  node_kernel<<<n, 128, 0, stream>>>(offs, deg, eids, ei, e_buf, Whb, side, Xb, E);

  // bi = X @ W_bi^T ; out = elu(leaky(Wh+side) + leaky(bi) + Wh)
  gemm_abt<<<ggrid, gblk, 0, stream>>>(Xb, Wbi, 128, 0, n, nullptr, 1, Whb, side,
                                       (float*)d_out);
}

// Round 4
// 289.165 us; speedup vs baseline: 1.2540x; 1.0325x over previous
//
#include <hip/hip_runtime.h>
#include <stdint.h>

#define SLOPE 0.2f
#define HASH_SIZE 131072  // 2^17, load factor ~0.38 at C=50000

__device__ __forceinline__ float leakyf(float x) { return x >= 0.f ? x : SLOPE * x; }
__device__ __forceinline__ float sigmoidf(float x) { return 1.f / (1.f + expf(-x)); }
__device__ __forceinline__ unsigned short f2bf(float f) {
  union { float f; unsigned int i; } c; c.f = f;
  unsigned int u = c.i;
  return (unsigned short)((u + 0x7fffu + ((u >> 16) & 1u)) >> 16);  // RNE
}
__device__ __forceinline__ float bf2f(unsigned short u) {
  union { unsigned int i; float f; } c; c.i = ((unsigned int)u) << 16; return c.f;
}
// unpack 4 consecutive bf16 (8B) -> float4
__device__ __forceinline__ float4 ldbf4(const unsigned short* p) {
  uint2 v = *(const uint2*)p;
  union { unsigned int i; float f; } a, b, c, d;
  a.i = v.x << 16; b.i = v.x & 0xffff0000u;
  c.i = v.y << 16; d.i = v.y & 0xffff0000u;
  return make_float4(a.f, b.f, c.f, d.f);
}

// ---------- init scratch (deg/cursor zero, hash empty) ----------
__global__ void init_kernel(int* __restrict__ deg, int* __restrict__ cursor,
                            int* __restrict__ hkeys, float* __restrict__ hval,
                            int n, int H)
{
  int i = blockIdx.x * blockDim.x + threadIdx.x;
  int stride = gridDim.x * blockDim.x;
  for (int j = i; j < n; j += stride) { deg[j] = 0; cursor[j] = 0; }
  for (int j = i; j < H; j += stride) { hkeys[j] = -1; hval[j] = 0.f; }
}

// ---------- constraint hash build ----------
__global__ void hash_build(const int* __restrict__ cidx, const float* __restrict__ cval,
                           const int* __restrict__ ctype, const float* __restrict__ lc,
                           int* __restrict__ hkeys, float* __restrict__ hval,
                           int C, int n, int H)
{
  int i = blockIdx.x * blockDim.x + threadIdx.x;
  if (i >= C) return;
  int key = cidx[i] * n + cidx[C + i];
  float l = sigmoidf(lc[ctype[i]]) * 0.9f + 0.1f;   // lc = sig*(1-0.1)+0.1
  float w = l * cval[i];
  unsigned int slot = ((unsigned int)key * 2654435761u) & (unsigned int)(H - 1);
  while (true) {
    int prev = atomicCAS(&hkeys[slot], -1, key);
    if (prev == -1 || prev == key) break;
    slot = (slot + 1) & (unsigned int)(H - 1);
  }
  atomicAdd(&hval[slot], w);
}

// ---------- per-relation precompute: P3b[r][j] = rel[r]·att_w1[j,256:384] + att_b1[j] ----------
__global__ __launch_bounds__(128) void p3b_kernel(const float* __restrict__ rel,
                                                  const float* __restrict__ aw1,
                                                  const float* __restrict__ ab1,
                                                  float* __restrict__ P3b)
{
  int r = blockIdx.x; int j = threadIdx.x;
  __shared__ float rl[128];
  rl[j] = rel[r * 128 + j];
  __syncthreads();
  float acc = ab1[j];
  const float* wrow = aw1 + j * 384 + 256;
  #pragma unroll 4
  for (int k = 0; k < 128; ++k) acc += rl[k] * wrow[k];
  P3b[r * 128 + j] = acc;
}

// ---------- shared GEMM body (64x64 tile, 4x4 microtile, K=128) ----------
__device__ __forceinline__ void gemm_body(
    const float* __restrict__ A, const float* __restrict__ B,
    int ldb, int boff, int M, int m0, int n0,
    float (&acc)[4][4], float (*As)[68], float (*Bs)[68])
{
  const int tid = threadIdx.x;
  const int tx = tid & 15, ty = tid >> 4;
  const int lin = tid * 4;
  const int lm = lin >> 4;        // 0..63
  const int lk = lin & 15;        // 0,4,8,12

  for (int kk = 0; kk < 128; kk += 16) {
    __syncthreads();
    {
      int row = m0 + lm;
      if (row < M) {
        float4 v = *(const float4*)(A + row * 128 + kk + lk);
        As[lk + 0][lm] = v.x; As[lk + 1][lm] = v.y;
        As[lk + 2][lm] = v.z; As[lk + 3][lm] = v.w;
      } else {
        As[lk + 0][lm] = 0.f; As[lk + 1][lm] = 0.f;
        As[lk + 2][lm] = 0.f; As[lk + 3][lm] = 0.f;
      }
      int j = n0 + lm;  // N=128 exact, no guard needed
      float4 w = *(const float4*)(B + j * ldb + boff + kk + lk);
      Bs[lk + 0][lm] = w.x; Bs[lk + 1][lm] = w.y;
      Bs[lk + 2][lm] = w.z; Bs[lk + 3][lm] = w.w;
    }
    __syncthreads();
    #pragma unroll
    for (int k = 0; k < 16; ++k) {
      float a[4], b[4];
      #pragma unroll
      for (int i = 0; i < 4; ++i) a[i] = As[k][ty * 4 + i];
      #pragma unroll
      for (int j = 0; j < 4; ++j) b[j] = Bs[k][tx * 4 + j];
      #pragma unroll
      for (int i = 0; i < 4; ++i)
        #pragma unroll
        for (int j = 0; j < 4; ++j)
          acc[i][j] += a[i] * b[j];
    }
  }
}

// ---------- GEMM: C = A @ B^T (fp32 store + optional bf16 copy, or fused final epilogue) ----------
__global__ __launch_bounds__(256) void gemm_abt(
    const float* __restrict__ A,
    const float* __restrict__ B, int ldb, int boff, int M,
    float* __restrict__ Cb, unsigned short* __restrict__ C16, int epi,
    const float* __restrict__ Whb,
    const float* __restrict__ side,
    float* __restrict__ outp)
{
  __shared__ float As[16][68];
  __shared__ float Bs[16][68];
  const int m0 = blockIdx.x * 64;
  const int n0 = blockIdx.y * 64;
  float acc[4][4] = {};
  gemm_body(A, B, ldb, boff, M, m0, n0, acc, As, Bs);

  const int tx = (int)threadIdx.x & 15, ty = (int)threadIdx.x >> 4;
  #pragma unroll
  for (int i = 0; i < 4; ++i) {
    int row = m0 + ty * 4 + i;
    if (row >= M) continue;
    int idx0 = row * 128 + n0 + tx * 4;
    if (epi == 0) {
      float4 v4 = make_float4(acc[i][0], acc[i][1], acc[i][2], acc[i][3]);
      *(float4*)(Cb + idx0) = v4;
      if (C16) {
        ushort4 u; u.x = f2bf(v4.x); u.y = f2bf(v4.y); u.z = f2bf(v4.z); u.w = f2bf(v4.w);
        *(ushort4*)(C16 + idx0) = u;
      }
    } else {
      #pragma unroll
      for (int j = 0; j < 4; ++j) {
        int idx = idx0 + j;
        float w = Whb[idx];
        float s = side[idx];
        float hn = leakyf(w + s) + leakyf(acc[i][j]) + w;
        outp[idx] = hn > 0.f ? hn : (expf(hn) - 1.f);
      }
    }
  }
}

// ---------- fused 4-matrix GEMM -> bf16 outputs: P1/P2 = Wh@A1/A2^T, Q1/Q2 = Wh@G1/G2^T ----------
__global__ __launch_bounds__(256) void gemm4(
    const float* __restrict__ A,
    const float* __restrict__ aw1, const float* __restrict__ gw1,
    unsigned short* __restrict__ P1, unsigned short* __restrict__ P2,
    unsigned short* __restrict__ Q1, unsigned short* __restrict__ Q2, int M)
{
  __shared__ float As[16][68];
  __shared__ float Bs[16][68];
  const int mat = blockIdx.y >> 1;
  const int n0 = (blockIdx.y & 1) * 64;
  const int m0 = blockIdx.x * 64;
  const float* B; int ldb, boff; unsigned short* out;
  switch (mat) {
    case 0:  B = aw1; ldb = 384; boff = 0;   out = P1; break;
    case 1:  B = aw1; ldb = 384; boff = 128; out = P2; break;
    case 2:  B = gw1; ldb = 256; boff = 0;   out = Q1; break;
    default: B = gw1; ldb = 256; boff = 128; out = Q2; break;
  }
  float acc[4][4] = {};
  gemm_body(A, B, ldb, boff, M, m0, n0, acc, As, Bs);

  const int tx = (int)threadIdx.x & 15, ty = (int)threadIdx.x >> 4;
  #pragma unroll
  for (int i = 0; i < 4; ++i) {
    int row = m0 + ty * 4 + i;
    if (row >= M) continue;
    ushort4 u;
    u.x = f2bf(acc[i][0]); u.y = f2bf(acc[i][1]);
    u.z = f2bf(acc[i][2]); u.w = f2bf(acc[i][3]);
    *(ushort4*)(out + row * 128 + n0 + tx * 4) = u;
  }
}

// ---------- degree count ----------
__global__ void deg_kernel(const int* __restrict__ ei, int* __restrict__ deg, int E)
{
  int i = blockIdx.x * blockDim.x + threadIdx.x;
  if (i < E) atomicAdd(&deg[ei[i]], 1);
}

// ---------- exclusive scan of deg -> offs (single block, shfl-based) ----------
__global__ __launch_bounds__(1024) void scan_kernel(const int* __restrict__ deg,
                                                    int* __restrict__ offs, int n)
{
  const int ITEMS = (n + 1023) >> 10;    // <=16
  const int t = threadIdx.x;
  const int base = t * ITEMS;
  int local[16];
  int sum = 0;
  for (int i = 0; i < ITEMS; ++i) {
    int idx = base + i;
    int v = (idx < n) ? deg[idx] : 0;
    local[i] = sum;           // exclusive prefix within chunk
    sum += v;
  }
  __shared__ int wsum[16];
  int lane = t & 63, w = t >> 6;
  int x = sum;
  #pragma unroll
  for (int d = 1; d < 64; d <<= 1) {
    int y = __shfl_up(x, d, 64);
    if (lane >= d) x += y;
  }
  if (lane == 63) wsum[w] = x;
  __syncthreads();
  if (t == 0) {
    int acc2 = 0;
    for (int i = 0; i < 16; ++i) { int v = wsum[i]; wsum[i] = acc2; acc2 += v; }
  }
  __syncthreads();
  int texcl = wsum[w] + (x - sum);
  for (int i = 0; i < ITEMS; ++i) {
    int idx = base + i;
    if (idx < n) offs[idx] = texcl + local[i];
  }
}

// ---------- bucket edges by src, materialize sorted src/tgt/rtype ----------
__global__ void place_kernel(const int* __restrict__ ei, const int* __restrict__ etype,
                             const int* __restrict__ offs, int* __restrict__ cursor,
                             int* __restrict__ src_s, int* __restrict__ tgt_s,
                             int* __restrict__ rt_s, int E)
{
  int i = blockIdx.x * blockDim.x + threadIdx.x;
  if (i >= E) return;
  int s = ei[i];
  int pos = offs[s] + atomicAdd(&cursor[s], 1);
  src_s[pos] = s;
  tgt_s[pos] = ei[E + i];
  rt_s[pos] = etype[i];
}

// ---------- per-edge (src-sorted order): 32 lanes/edge, bf16 table gathers ----------
__global__ __launch_bounds__(256) void edge_kernel(
  const int* __restrict__ src_s, const int* __restrict__ tgt_s, const int* __restrict__ rt_s,
  const unsigned short* __restrict__ P1, const unsigned short* __restrict__ P2,
  const float* __restrict__ P3b,
  const unsigned short* __restrict__ Q1, const unsigned short* __restrict__ Q2,
  const float* __restrict__ aw2,
  const float* __restrict__ gb1, const float* __restrict__ gw2,
  const float* __restrict__ gb2, const float* __restrict__ lgp,
  const int* __restrict__ hkeys, const float* __restrict__ hval,
  float* __restrict__ e_sorted, int E, int n, int H)
{
  int wid = blockIdx.x * 8 + ((int)threadIdx.x >> 5);   // sorted edge slot
  if (wid >= E) return;
  int l = threadIdx.x & 31;
  int src = src_s[wid], tgt = tgt_s[wid], rt = rt_s[wid];

  float4 p1 = ldbf4(P1 + src * 128 + 4 * l);
  float4 p2 = ldbf4(P2 + tgt * 128 + 4 * l);
  float4 p3 = *(const float4*)(P3b + rt * 128 + 4 * l);
  float4 w2 = *(const float4*)(aw2 + 4 * l);
  float part = leakyf(p1.x + p2.x + p3.x) * w2.x
             + leakyf(p1.y + p2.y + p3.y) * w2.y
             + leakyf(p1.z + p2.z + p3.z) * w2.z
             + leakyf(p1.w + p2.w + p3.w) * w2.w;
  #pragma unroll
  for (int k = 16; k; k >>= 1) part += __shfl_xor(part, k, 64);  // masks<32: stays in 32-lane group
  float e = part;

  // hash lookup: mask & c_agg
  int key = src * n + tgt;
  unsigned int slot = ((unsigned int)key * 2654435761u) & (unsigned int)(H - 1);
  int fslot = -1;
  while (true) {
    int kk = hkeys[slot];
    if (kk == key) { fslot = (int)slot; break; }
    if (kk == -1) break;
    slot = (slot + 1) & (unsigned int)(H - 1);
  }
  if (fslot >= 0) {  // group-uniform branch
    float ms = hval[fslot];
    float4 q1 = ldbf4(Q1 + src * 128 + 4 * l);
    float4 q2 = ldbf4(Q2 + tgt * 128 + 4 * l);
    float4 b1 = *(const float4*)(gb1 + 4 * l);
    float4 g2 = *(const float4*)(gw2 + 4 * l);
    float gp = leakyf(q1.x + q2.x + b1.x) * g2.x
             + leakyf(q1.y + q2.y + b1.y) * g2.y
             + leakyf(q1.z + q2.z + b1.z) * g2.z
             + leakyf(q1.w + q2.w + b1.w) * g2.w;
    #pragma unroll
    for (int k = 16; k; k >>= 1) gp += __shfl_xor(gp, k, 64);
    float g = sigmoidf(gp + gb2[0]);
    float lg = sigmoidf(lgp[0]) * 0.9f + 0.1f;
    e += lg * (g * ms);    // n_matched > 0 structurally (constraints copy first C edges)
  }
  if (l == 0) e_sorted[wid] = e;
}

// ---------- per-node softmax + aggregation (contiguous CSR reads, bf16 Wh gather) ----------
__global__ __launch_bounds__(128) void node_kernel(
  const int* __restrict__ offs, const int* __restrict__ deg,
  const int* __restrict__ tgt_s, const float* __restrict__ e_sorted,
  const unsigned short* __restrict__ Whb16, const float* __restrict__ Whb,
  float* __restrict__ side, float* __restrict__ Xb)
{
  const int node = blockIdx.x;
  const int t = threadIdx.x;
  const int start = offs[node];
  const int cnt = deg[node];
  __shared__ float red2[2];
  __shared__ int sh_t[128];
  __shared__ float sh_e[128];

  float m = -INFINITY;
  for (int j = t; j < cnt; j += 128) m = fmaxf(m, e_sorted[start + j]);
  #pragma unroll
  for (int k = 32; k; k >>= 1) m = fmaxf(m, __shfl_xor(m, k, 64));
  if ((t & 63) == 0) red2[t >> 6] = m;
  __syncthreads();
  m = fmaxf(red2[0], red2[1]);

  float acc = 0.f, ssum = 0.f;
  for (int base = 0; base < cnt; base += 128) {
    int jmax = min(128, cnt - base);
    __syncthreads();
    if (t < jmax) {
      sh_t[t] = tgt_s[start + base + t] * 128;
      sh_e[t] = expf(fminf(e_sorted[start + base + t] - m, 20.f));   // exp once per edge
    }
    __syncthreads();
    int j = 0;
    for (; j + 4 <= jmax; j += 4) {
      int t0 = sh_t[j], t1 = sh_t[j+1], t2 = sh_t[j+2], t3 = sh_t[j+3];
      float e0 = sh_e[j], e1 = sh_e[j+1], e2 = sh_e[j+2], e3 = sh_e[j+3];
      float w0 = bf2f(Whb16[t0 + t]), w1 = bf2f(Whb16[t1 + t]);
      float w2 = bf2f(Whb16[t2 + t]), w3 = bf2f(Whb16[t3 + t]);
      ssum += (e0 + e1) + (e2 + e3);
      acc += e0 * w0 + e1 * w1 + e2 * w2 + e3 * w3;
    }
    for (; j < jmax; ++j) {
      float ex = sh_e[j];
      ssum += ex;
      acc += ex * bf2f(Whb16[sh_t[j] + t]);
    }
  }
  float s = acc / (ssum + 1e-10f);
  int idx = node * 128 + t;
  side[idx] = s;
  Xb[idx] = Whb[idx] * s;
}

// ---------- launch ----------
extern "C" void kernel_launch(void* const* d_in, const int* in_sizes, int n_in,
                              void* d_out, int out_size, void* d_ws, size_t ws_size,
                              hipStream_t stream)
{
  const float* h    = (const float*)d_in[0];
  const int* ei     = (const int*)d_in[1];
  const int* etype  = (const int*)d_in[2];
  const float* rel  = (const float*)d_in[3];
  const int* cidx   = (const int*)d_in[4];
  const float* cval = (const float*)d_in[5];
  const int* ctype  = (const int*)d_in[6];
  const float* W    = (const float*)d_in[7];
  const float* Wbi  = (const float*)d_in[8];
  const float* aw1  = (const float*)d_in[9];
  const float* ab1  = (const float*)d_in[10];
  const float* aw2  = (const float*)d_in[11];
  const float* gw1  = (const float*)d_in[12];
  const float* gb1  = (const float*)d_in[13];
  const float* gw2  = (const float*)d_in[14];
  const float* gb2  = (const float*)d_in[15];
  const float* lc   = (const float*)d_in[16];
  const float* lgp  = (const float*)d_in[17];

  const int n = in_sizes[0] / 128;   // 10000
  const int E = in_sizes[2];         // 320000
  const int C = in_sizes[6];         // 50000
  const int R = in_sizes[3] / 128;   // 20
  const int H = HASH_SIZE;

  // scratch layout (~35 MB)
  char* ws = (char*)d_ws;
  size_t off = 0;
  auto alloc = [&](size_t bytes) -> void* {
    void* p = ws + off;
    off = (off + bytes + 255) & ~(size_t)255;
    return p;
  };
  float* Whb            = (float*)alloc((size_t)n * 128 * 4);
  unsigned short* Whb16 = (unsigned short*)alloc((size_t)n * 128 * 2);
  unsigned short* P1b   = (unsigned short*)alloc((size_t)n * 128 * 2);
  unsigned short* P2b   = (unsigned short*)alloc((size_t)n * 128 * 2);
  unsigned short* Q1b   = (unsigned short*)alloc((size_t)n * 128 * 2);
  unsigned short* Q2b   = (unsigned short*)alloc((size_t)n * 128 * 2);
  float* Xb    = (float*)alloc((size_t)n * 128 * 4);
  float* P3b   = (float*)alloc((size_t)R * 128 * 4);
  float* side  = (float*)alloc((size_t)n * 128 * 4);
  float* e_sorted = (float*)alloc((size_t)E * 4);
  int* src_s   = (int*)alloc((size_t)E * 4);
  int* tgt_s   = (int*)alloc((size_t)E * 4);
  int* rt_s    = (int*)alloc((size_t)E * 4);
  int* deg     = (int*)alloc((size_t)n * 4);
  int* cursor  = (int*)alloc((size_t)n * 4);
  int* offs    = (int*)alloc((size_t)(n + 1) * 4);
  int* hkeys   = (int*)alloc((size_t)H * 4);
  float* hval  = (float*)alloc((size_t)H * 4);
  (void)ws_size; (void)n_in; (void)out_size;

  dim3 gblk(256);
  dim3 ggrid((n + 63) / 64, 2);

  init_kernel<<<256, 256, 0, stream>>>(deg, cursor, hkeys, hval, n, H);
  hash_build<<<(C + 255) / 256, 256, 0, stream>>>(cidx, cval, ctype, lc, hkeys, hval, C, n, H);
  deg_kernel<<<(E + 255) / 256, 256, 0, stream>>>(ei, deg, E);
  scan_kernel<<<1, 1024, 0, stream>>>(deg, offs, n);
  place_kernel<<<(E + 255) / 256, 256, 0, stream>>>(ei, etype, offs, cursor,
                                                    src_s, tgt_s, rt_s, E);

  // Wh = h @ W^T (fp32 + bf16 copy)
  gemm_abt<<<ggrid, gblk, 0, stream>>>(h, W, 128, 0, n, Whb, Whb16, 0,
                                       nullptr, nullptr, nullptr);
  p3b_kernel<<<R, 128, 0, stream>>>(rel, aw1, ab1, P3b);
  // P1,P2,Q1,Q2 (bf16) in one dispatch
  gemm4<<<dim3((n + 63) / 64, 8), gblk, 0, stream>>>(Whb, aw1, gw1, P1b, P2b, Q1b, Q2b, n);

  edge_kernel<<<(E + 7) / 8, 256, 0, stream>>>(src_s, tgt_s, rt_s, P1b, P2b, P3b,
                                               Q1b, Q2b, aw2, gb1, gw2, gb2, lgp,
                                               hkeys, hval, e_sorted, E, n, H);
  node_kernel<<<n, 128, 0, stream>>>(offs, deg, tgt_s, e_sorted, Whb16, Whb, side, Xb);

  // bi = X @ W_bi^T ; out = elu(leaky(Wh+side) + leaky(bi) + Wh)
  gemm_abt<<<ggrid, gblk, 0, stream>>>(Xb, Wbi, 128, 0, n, nullptr, nullptr, 1,
                                       Whb, side, (float*)d_out);
}